// Round 6
// baseline (468.270 us; speedup 1.0000x reference)
//
#include <hip/hip_runtime.h>

// VQ-VAE codebook quantization, MI355X (gfx950)
// z: [32, 256, 32, 32] fp32 ; codebook: [1024, 256] fp32
// outputs (concat fp32): z_q [32,256,32,32] (8388608) | idx [32768] | loss [1]
//
// idx contract: match numpy fp32 argmin of dist = fl( fl(znorm+enorm) - 2*dot ),
// ties -> lowest index (verified R2-R5). enorm sequence bit-identical to R2's
// kernel (float4 fmaf chain + 6-step xor tree; R3 verified the in-kernel fold).
// znorm fp64 (uniform exact-ulp per-row shift -> argmin invariant).
//
// REGISTER BUDGET (R3/R4/R5 post-mortem): every 1024-thread variant —
// __launch_bounds__(1024,1), (1024,4), amdgpu_waves_per_eu(4,4) — got a
// 64-VGPR cap and spilled 100-400 MB to scratch. 512 threads with
// __launch_bounds__(512,2) is the empirically-good shape: R2 measured
// 96 VGPR, WRITE_SIZE exactly ideal (32.9 MB), zero scratch. Do not go back
// to 1024-thread blocks.
//
// Es layout XOR-swizzled at float4 granularity:
//   element (r, k) -> Es[r*256 + (((k>>2) ^ r)<<2 | (k&3))]
// Thread k-ownership split {tx*4..+3} u {128+tx*4..+3} so each ds_read_b128
// covers 32 consecutive (permuted) float4s -> conflict-free; stores <=2-way.

#define D_DIM   256
#define K_CODES 1024
#define HW      1024
#define MT      128     // positions per block
#define NT      256     // codes per N-chunk (Es logical row, swizzled)
#define BK      16      // d-chunk per barrier
#define THREADS 512     // 8 waves; 1 block/CU via LDS; 2 waves/SIMD

#define IDX_OFF  8388608
#define LOSS_OFF 8421376

// LDS (floats): As[256*128] | Es[16*256] | enorm_lds[1024] | bestm[128] | znorm_s[128]
#define AS_F   (D_DIM*MT)                      // 32768
#define ES_F   (BK*NT)                         // 4096 (>= 1024 fp64 znorm partials)
#define EN_F   (K_CODES)                       // 1024
#define SMEM_FLOATS (AS_F + ES_F + EN_F + MT + MT)   // 38144
#define SMEM_BYTES  (SMEM_FLOATS * 4)                // 152576 B < 160 KiB

extern __shared__ float smem[];

__global__ __launch_bounds__(THREADS, 2) void vq_kernel(
        const float* __restrict__ z, const float* __restrict__ cb,
        float* __restrict__ out)
{
    float* As        = smem;                               // [256][128]
    float* Es        = smem + AS_F;                        // [16][256] swizzled
    float* enorm_lds = smem + AS_F + ES_F;                 // [1024]
    int*   bestm     = (int*)(smem + AS_F + ES_F + EN_F);  // [128]
    float* znorm_s   = smem + AS_F + ES_F + EN_F + MT;     // [128]

    const int t   = threadIdx.x;
    const int blk = blockIdx.x;          // 256 blocks = 1/CU
    const int b   = blk >> 3;
    const int p0  = (blk & 7) * MT;
    const float* zb = z + (size_t)b * D_DIM * HW;

    // E-staging thread mapping: thread t stages codebook row ek, float4 cols
    // {2*eh, 2*eh+1} (rows r = 8*eh .. 8*eh+7). Lane pairs cover 64 B/row ->
    // coalesced global reads; L2-resident codebook.
    const int ek  = t >> 1;              // code row 0..255
    const int eh  = t & 1;
    const int ec4 = ek >> 2, ek3 = ek & 3;   // swizzle components
    float4 vn0 = *(const float4*)(cb + (size_t)ek * D_DIM + eh * 8);
    float4 vn1 = *(const float4*)(cb + (size_t)ek * D_DIM + eh * 8 + 4);

    // ---- stage A^T [256][128], z read from HBM once, coalesced float4 ----
    for (int i = t; i < D_DIM * MT / 4; i += THREADS) {
        int d = i >> 5, m4 = i & 31;
        *(float4*)(As + d * MT + m4 * 4) = *(const float4*)(zb + d * HW + p0 + m4 * 4);
    }
    __syncthreads();

    // ---- znorm[m]: fp64 column sum -> fp32 (zscr overlays Es) ----
    {
        int m = t & (MT - 1), q = t >> 7;            // 4 segments x 64 d
        const float* col = As + m;
        double zp = 0.0;
        #pragma unroll 8
        for (int d = q * 64; d < q * 64 + 64; ++d) {
            double v = (double)col[d * MT];          // 2 lanes/bank = free
            zp = fma(v, v, zp);
        }
        double* zscr = (double*)Es;                  // 512 doubles = 4 KB
        zscr[q * MT + m] = zp;
    }
    __syncthreads();
    if (t < MT) {
        double* zscr = (double*)Es;
        double s = (zscr[t] + zscr[MT + t]) + (zscr[2*MT + t] + zscr[3*MT + t]);
        znorm_s[t] = (float)s;
    }

    // ---- enorm in-kernel: BIT-IDENTICAL per-row sequence to R2's enorm_kernel
    //      (float4 fmaf chain + 6-step xor tree), 8 waves x 128 rows ----
    {
        int w = t >> 6, lane = t & 63;
        #pragma unroll 4
        for (int r = 0; r < 128; ++r) {
            int k = w * 128 + r;
            float4 v = *(const float4*)(cb + (size_t)k * D_DIM + lane * 4);
            float s = fmaf(v.x, v.x, fmaf(v.y, v.y, fmaf(v.z, v.z, v.w * v.w)));
            #pragma unroll
            for (int off = 32; off; off >>= 1) s += __shfl_xor(s, off);
            if (lane == 0) enorm_lds[k] = s;
        }
    }
    __syncthreads();   // znorm_s + enorm_lds ready; Es free

    const int tx = t & 31, ty = t >> 5;  // 16 ty-groups x 8 m = 128 positions
    const int m_base = ty * 8;
    const int kx = tx * 4;               // k-ownership: {kx..kx+3} u {128+kx..+3}

    float znf[8];
    #pragma unroll
    for (int i = 0; i < 8; ++i) znf[i] = znorm_s[m_base + i];

    float bestv[8]; int besti[8];
    #pragma unroll
    for (int i = 0; i < 8; ++i) { bestv[i] = 3.4e38f; besti[i] = 0; }

    float acc[8][8];

    // ---- GEMM: 64 tiles = 4 k-chunks x 16 d-chunks, reg-prefetched E staging ----
    for (int s = 0; s < 64; ++s) {
        __syncthreads();                 // all waves done reading previous Es tile
        {
            // store 8 rows r = 8*eh + 0..7; per-instr bank pattern <=2-way (free)
            int r0 = eh * 8;
            Es[(r0 + 0) * NT + (((ec4 ^ (r0 + 0)) << 2) | ek3)] = vn0.x;
            Es[(r0 + 1) * NT + (((ec4 ^ (r0 + 1)) << 2) | ek3)] = vn0.y;
            Es[(r0 + 2) * NT + (((ec4 ^ (r0 + 2)) << 2) | ek3)] = vn0.z;
            Es[(r0 + 3) * NT + (((ec4 ^ (r0 + 3)) << 2) | ek3)] = vn0.w;
            Es[(r0 + 4) * NT + (((ec4 ^ (r0 + 4)) << 2) | ek3)] = vn1.x;
            Es[(r0 + 5) * NT + (((ec4 ^ (r0 + 5)) << 2) | ek3)] = vn1.y;
            Es[(r0 + 6) * NT + (((ec4 ^ (r0 + 6)) << 2) | ek3)] = vn1.z;
            Es[(r0 + 7) * NT + (((ec4 ^ (r0 + 7)) << 2) | ek3)] = vn1.w;
        }
        __syncthreads();
        if (s < 63) {                    // prefetch next tile (L2-resident)
            int s1 = s + 1, c1 = s1 >> 4, dk1 = (s1 & 15) * BK;
            const float* src = cb + (size_t)(c1 * NT + ek) * D_DIM + dk1 + eh * 8;
            vn0 = *(const float4*)(src);
            vn1 = *(const float4*)(src + 4);
        }
        if ((s & 15) == 0) {
            #pragma unroll
            for (int i = 0; i < 8; ++i)
                #pragma unroll
                for (int j = 0; j < 8; ++j) acc[i][j] = 0.f;
        }
        const int dka = (s & 15) * BK;
        #pragma unroll
        for (int dd = 0; dd < BK; ++dd) {
            float a[8], e[8];
            *(float4*)(a)     = *(const float4*)(As + (dka + dd) * MT + m_base);     // broadcast
            *(float4*)(a + 4) = *(const float4*)(As + (dka + dd) * MT + m_base + 4); // broadcast
            const float* er = Es + dd * NT + ((tx ^ dd) << 2);   // swizzled, conflict-free
            *(float4*)(e)     = *(const float4*)(er);            // k = kx..kx+3
            *(float4*)(e + 4) = *(const float4*)(er + 128);      // k = 128+kx..+3
            #pragma unroll
            for (int i = 0; i < 8; ++i)
                #pragma unroll
                for (int j = 0; j < 8; ++j)
                    acc[i][j] = fmaf(a[i], e[j], acc[i][j]);
        }
        if ((s & 15) == 15) {            // chunk epilogue: np-style double rounding
            int k0 = (s >> 4) * NT;
            float bn[8];
            *(float4*)(bn)     = *(const float4*)(enorm_lds + k0 + kx);
            *(float4*)(bn + 4) = *(const float4*)(enorm_lds + k0 + 128 + kx);
            #pragma unroll
            for (int j = 0; j < 8; ++j) {
                int kidx = k0 + (j < 4 ? kx + j : 128 + kx + (j - 4));
                #pragma unroll
                for (int i = 0; i < 8; ++i) {
                    float A   = znf[i] + bn[j];        // rounds at ~256 scale
                    float val = A - 2.0f * acc[i][j];  // 2*acc exact; single rounding
                    if (val < bestv[i] || (val == bestv[i] && kidx < besti[i])) {
                        bestv[i] = val; besti[i] = kidx;
                    }
                }
            }
        }
    }

    // ---- argmin across the 32-lane half-wave k dimension, lowest index ties ----
    #pragma unroll
    for (int i = 0; i < 8; ++i) {
        float v = bestv[i]; int ix = besti[i];
        #pragma unroll
        for (int off = 16; off; off >>= 1) {
            float ov = __shfl_xor(v, off);
            int   oi = __shfl_xor(ix, off);
            if (ov < v || (ov == v && oi < ix)) { v = ov; ix = oi; }
        }
        if (tx == 0) {
            bestm[m_base + i] = ix;
            out[IDX_OFF + (size_t)blk * MT + m_base + i] = (float)ix;
        }
    }
    __syncthreads();

    // ---- epilogue: gather codebook rows (L2), write z_q coalesced, loss ----
    float lsum = 0.f;
    const size_t zq_base = (size_t)b * D_DIM * HW + p0;
    for (int i2 = t; i2 < D_DIM * MT / 4; i2 += THREADS) {
        int p = i2 & (MT - 1), d4 = i2 >> 7;
        int idx = bestm[p];
        float4 cv = *(const float4*)(cb + (size_t)idx * D_DIM + d4 * 4);
        float z0 = As[(d4 * 4 + 0) * MT + p];
        float z1 = As[(d4 * 4 + 1) * MT + p];
        float z2 = As[(d4 * 4 + 2) * MT + p];
        float z3 = As[(d4 * 4 + 3) * MT + p];
        float e0 = cv.x - z0, e1 = cv.y - z1, e2 = cv.z - z2, e3 = cv.w - z3;
        lsum = fmaf(e0, e0, lsum); lsum = fmaf(e1, e1, lsum);
        lsum = fmaf(e2, e2, lsum); lsum = fmaf(e3, e3, lsum);
        out[zq_base + (size_t)(d4 * 4 + 0) * HW + p] = cv.x;
        out[zq_base + (size_t)(d4 * 4 + 1) * HW + p] = cv.y;
        out[zq_base + (size_t)(d4 * 4 + 2) * HW + p] = cv.z;
        out[zq_base + (size_t)(d4 * 4 + 3) * HW + p] = cv.w;
    }
    #pragma unroll
    for (int off = 32; off; off >>= 1) lsum += __shfl_xor(lsum, off);
    __syncthreads();
    if ((t & 63) == 0) Es[t >> 6] = lsum;   // 8 wave partials
    __syncthreads();
    if (t == 0) {
        float ssum = 0.f;
        #pragma unroll
        for (int w = 0; w < 8; ++w) ssum += Es[w];
        atomicAdd(out + LOSS_OFF, ssum * (1.25f / 8388608.f));
    }
}

extern "C" void kernel_launch(void* const* d_in, const int* in_sizes, int n_in,
                              void* d_out, int out_size, void* d_ws, size_t ws_size,
                              hipStream_t stream) {
    const float* z  = (const float*)d_in[0];
    const float* cb = (const float*)d_in[1];
    float* out = (float*)d_out;

    // loss slot accumulated via atomics -> zero it (d_out poisoned 0xAA each launch)
    hipMemsetAsync(out + LOSS_OFF, 0, sizeof(float), stream);

    hipFuncSetAttribute((const void*)vq_kernel,
                        hipFuncAttributeMaxDynamicSharedMemorySize, SMEM_BYTES);
    vq_kernel<<<256, THREADS, SMEM_BYTES, stream>>>(z, cb, out);
}

// Round 7
// 313.352 us; speedup vs baseline: 1.4944x; 1.4944x over previous
//
#include <hip/hip_runtime.h>

// VQ-VAE codebook quantization, MI355X (gfx950)
// z: [32, 256, 32, 32] fp32 ; codebook: [1024, 256] fp32
// outputs (concat fp32): z_q [32,256,32,32] (8388608) | idx [32768] | loss [1]
//
// idx contract: match numpy fp32 argmin of dist = fl( fl(znorm+enorm) - 2*dot ),
// ties -> lowest index (verified R2-R6). enorm from the R2 enorm_kernel
// (bit-exact sequence); znorm fp64 (uniform exact-ulp row shift -> argmin
// invariant).
//
// REGISTER DISCIPLINE (R3-R6 post-mortems): the ONLY verified no-spill shape
// is 512 threads + __launch_bounds__(512,2) + R2's register footprint
// (96 VGPR, WRITE_SIZE bit-ideal 32.9 MB). Every addition of prefetch
// registers / in-kernel enorm / 1024-thread blocks caused 100-400 MB of
// scratch spill traffic. This file is R2 VERBATIM except the Es swizzle.
//
// Es conflict fix (functionally verified in R6, which passed):
//   - lane k-ownership {tx*4..+3} u {128+tx*4..+3}
//   - Es element (r,k) stored at r*256 + (((k>>2)^r)<<2 | (k&3))
//   -> ds_read_b128 lanes cover all 8 16B-bank-groups (min-phase);
//      staging stores <=2-way aliased (free per m136).

#define D_DIM   256
#define K_CODES 1024
#define HW      1024
#define MT      128     // positions per block
#define NT      256     // codes per N-chunk
#define BK      16      // d-chunk staged per barrier
#define THREADS 512

#define IDX_OFF  8388608
#define LOSS_OFF 8421376

// As[256*128] + Es[16*256] + bestm[128] + znorm_s[128]
#define AS_F   (D_DIM*MT)                      // 32768
#define ES_F   (BK*NT)                         // 4096 (also holds 512 fp64 znorm partials)
#define SMEM_FLOATS (AS_F + ES_F + MT + MT)    // 37120
#define SMEM_BYTES  (SMEM_FLOATS * 4)          // 148480 B < 160 KiB

extern __shared__ float smem[];

// enorm[k] = fp32 sum of cb[k][d]^2 — bit-identical sequence to R2 (passed).
__global__ void enorm_kernel(const float* __restrict__ cb, float* __restrict__ enorm) {
    int gt = blockIdx.x * blockDim.x + threadIdx.x;
    int k = gt >> 6;
    int lane = gt & 63;
    const float4* row = (const float4*)(cb + (size_t)k * D_DIM);
    float4 v = row[lane];
    float s = fmaf(v.x, v.x, fmaf(v.y, v.y, fmaf(v.z, v.z, v.w * v.w)));
    #pragma unroll
    for (int off = 32; off; off >>= 1) s += __shfl_xor(s, off);
    if (lane == 0) enorm[k] = s;
}

__global__ __launch_bounds__(THREADS, 2) void vq_kernel(
        const float* __restrict__ z, const float* __restrict__ cb,
        const float* __restrict__ enorm, float* __restrict__ out)
{
    float* As      = smem;                           // [256][128]
    float* Es      = smem + AS_F;                    // [16][256] swizzled
    int*   bestm   = (int*)(smem + AS_F + ES_F);     // [128]
    float* znorm_s = smem + AS_F + ES_F + MT;        // [128]

    const int t   = threadIdx.x;
    const int blk = blockIdx.x;          // 256 blocks = 1/CU
    const int b   = blk >> 3;
    const int p0  = (blk & 7) * MT;
    const float* zb = z + (size_t)b * D_DIM * HW;

    // ---- stage A^T [256][128] (z read from HBM once, coalesced float4) ----
    for (int i = t; i < D_DIM * MT / 4; i += THREADS) {
        int d = i >> 5, m4 = i & 31;
        *(float4*)(As + d * MT + m4 * 4) = *(const float4*)(zb + d * HW + p0 + m4 * 4);
    }
    __syncthreads();

    // ---- znorm[m] = fp64 sum of As[:,m]^2, rounded to fp32 (R2 verbatim) ----
    {
        int m = t & (MT - 1), q = t >> 7;            // 4 quarters of d
        const float* col = As + m;
        double zp = 0.0;
        #pragma unroll 8
        for (int d = q * 64; d < q * 64 + 64; ++d) {
            double v = (double)col[d * MT];
            zp += v * v;
        }
        double* zscr = (double*)Es;                  // 512 doubles = 4 KB
        zscr[q * MT + m] = zp;
    }
    __syncthreads();
    if (t < MT) {
        double* zscr = (double*)Es;
        double s = (zscr[t] + zscr[MT + t]) + (zscr[2 * MT + t] + zscr[3 * MT + t]);
        znorm_s[t] = (float)s;
    }
    __syncthreads();

    const int tx = t & 31, ty = t >> 5;  // wave = 2 ty-groups x 32 tx -> A reads broadcast
    const int m_base = ty * 8;           // 16 ty * 8 = 128 positions
    const int kx = tx * 4;               // k-ownership: {kx..kx+3} u {128+kx..+3}

    float znf[8];
    #pragma unroll
    for (int i = 0; i < 8; ++i) znf[i] = znorm_s[m_base + i];

    float bestv[8]; int besti[8];
    #pragma unroll
    for (int i = 0; i < 8; ++i) { bestv[i] = 3.4e38f; besti[i] = 0; }

    for (int c = 0; c < 4; ++c) {        // N-chunks over 1024 codes
        const int k0 = c * NT;
        float acc[8][8];
        #pragma unroll
        for (int i = 0; i < 8; ++i)
            #pragma unroll
            for (int j = 0; j < 8; ++j) acc[i][j] = 0.f;

        for (int dk = 0; dk < D_DIM; dk += BK) {
            __syncthreads();
            // stage E tile, swizzled: Es[(d4*4+c)*256 + swz(kk)] = cb[k0+kk][dk+d4*4+c]
            for (int i = t; i < BK * NT / 4; i += THREADS) {
                int kk = i >> 2, d4 = i & 3;
                float4 v = *(const float4*)(cb + (size_t)(k0 + kk) * D_DIM + dk + d4 * 4);
                int kc4 = kk >> 2, klo = kk & 3;
                int r0 = d4 * 4;
                Es[(r0 + 0) * NT + (((kc4 ^ (r0 + 0)) << 2) | klo)] = v.x;
                Es[(r0 + 1) * NT + (((kc4 ^ (r0 + 1)) << 2) | klo)] = v.y;
                Es[(r0 + 2) * NT + (((kc4 ^ (r0 + 2)) << 2) | klo)] = v.z;
                Es[(r0 + 3) * NT + (((kc4 ^ (r0 + 3)) << 2) | klo)] = v.w;
            }
            __syncthreads();
            #pragma unroll
            for (int dd = 0; dd < BK; ++dd) {
                float a[8], e[8];
                *(float4*)(a)     = *(const float4*)(As + (dk + dd) * MT + m_base);     // broadcast
                *(float4*)(a + 4) = *(const float4*)(As + (dk + dd) * MT + m_base + 4); // broadcast
                const float* er = Es + dd * NT + ((tx ^ dd) << 2);   // min-phase swizzled
                *(float4*)(e)     = *(const float4*)(er);            // k = kx..kx+3
                *(float4*)(e + 4) = *(const float4*)(er + 128);      // k = 128+kx..+3
                #pragma unroll
                for (int i = 0; i < 8; ++i)
                    #pragma unroll
                    for (int j = 0; j < 8; ++j)
                        acc[i][j] = fmaf(a[i], e[j], acc[i][j]);
            }
        }
        // chunk epilogue: dist = fl( fl(znorm + enorm_k) - 2*dot ), np-style
        {
            float bn[8];
            *(float4*)(bn)     = *(const float4*)(enorm + k0 + kx);
            *(float4*)(bn + 4) = *(const float4*)(enorm + k0 + 128 + kx);
            #pragma unroll
            for (int j = 0; j < 8; ++j) {
                int kidx = k0 + (j < 4 ? kx + j : 128 + kx + (j - 4));
                #pragma unroll
                for (int i = 0; i < 8; ++i) {
                    float A   = znf[i] + bn[j];        // rounds at ~256 scale
                    float val = A - 2.0f * acc[i][j];  // 2*acc exact; single rounding
                    if (val < bestv[i] || (val == bestv[i] && kidx < besti[i])) {
                        bestv[i] = val; besti[i] = kidx;
                    }
                }
            }
        }
    }

    // ---- argmin reduce across tx (32 lanes = half-wave), lowest index ties ----
    #pragma unroll
    for (int i = 0; i < 8; ++i) {
        float v = bestv[i]; int ix = besti[i];
        #pragma unroll
        for (int off = 16; off; off >>= 1) {
            float ov = __shfl_xor(v, off);
            int   oi = __shfl_xor(ix, off);
            if (ov < v || (ov == v && oi < ix)) { v = ov; ix = oi; }
        }
        if (tx == 0) {
            bestm[m_base + i] = ix;
            out[IDX_OFF + (size_t)blk * MT + m_base + i] = (float)ix;
        }
    }
    __syncthreads();

    // ---- epilogue: gather codebook rows (L2), write z_q coalesced, loss ----
    float lsum = 0.f;
    const size_t zq_base = (size_t)b * D_DIM * HW + p0;
    for (int i2 = t; i2 < D_DIM * MT / 4; i2 += THREADS) {
        int p = i2 & (MT - 1), d4 = i2 >> 7;
        int idx = bestm[p];
        float4 cv = *(const float4*)(cb + (size_t)idx * D_DIM + d4 * 4);
        float z0 = As[(d4 * 4 + 0) * MT + p];
        float z1 = As[(d4 * 4 + 1) * MT + p];
        float z2 = As[(d4 * 4 + 2) * MT + p];
        float z3 = As[(d4 * 4 + 3) * MT + p];
        float e0 = cv.x - z0, e1 = cv.y - z1, e2 = cv.z - z2, e3 = cv.w - z3;
        lsum = fmaf(e0, e0, lsum); lsum = fmaf(e1, e1, lsum);
        lsum = fmaf(e2, e2, lsum); lsum = fmaf(e3, e3, lsum);
        out[zq_base + (size_t)(d4 * 4 + 0) * HW + p] = cv.x;
        out[zq_base + (size_t)(d4 * 4 + 1) * HW + p] = cv.y;
        out[zq_base + (size_t)(d4 * 4 + 2) * HW + p] = cv.z;
        out[zq_base + (size_t)(d4 * 4 + 3) * HW + p] = cv.w;
    }
    #pragma unroll
    for (int off = 32; off; off >>= 1) lsum += __shfl_xor(lsum, off);
    __syncthreads();
    if ((t & 63) == 0) Es[t >> 6] = lsum;   // 8 wave partials
    __syncthreads();
    if (t == 0) {
        float s = 0.f;
        #pragma unroll
        for (int w = 0; w < 8; ++w) s += Es[w];
        atomicAdd(out + LOSS_OFF, s * (1.25f / 8388608.f));  // loss = 1.25*mean((zq-z)^2)
    }
}

extern "C" void kernel_launch(void* const* d_in, const int* in_sizes, int n_in,
                              void* d_out, int out_size, void* d_ws, size_t ws_size,
                              hipStream_t stream) {
    const float* z  = (const float*)d_in[0];
    const float* cb = (const float*)d_in[1];
    float* out = (float*)d_out;
    float* enorm = (float*)d_ws;

    // loss slot accumulated via atomics -> zero it (d_out poisoned 0xAA each launch)
    hipMemsetAsync(out + LOSS_OFF, 0, sizeof(float), stream);

    enorm_kernel<<<256, 256, 0, stream>>>(cb, enorm);

    hipFuncSetAttribute((const void*)vq_kernel,
                        hipFuncAttributeMaxDynamicSharedMemorySize, SMEM_BYTES);
    vq_kernel<<<256, THREADS, SMEM_BYTES, stream>>>(z, cb, enorm, out);
}